// Round 4
// baseline (350.360 us; speedup 1.0000x reference)
//
#include <hip/hip_runtime.h>
#include <hip/hip_bf16.h>
#include <hip/hip_fp16.h>

#define N_NODES 50000
#define D_IN    128
#define D_OUT   64
#define N_EDGES 800000
#define BROWS   128   // rows per block in gemm tile
#define XS_LD   68    // Xs row stride in floats: 16B-aligned, rowg banks 4g%32 -> conflict-free

// ---------------------------------------------------------------------------
// Kernel 1: X' = X @ W, output fp16. fp32 math on vector ALU (no fp32 MFMA).
// R3 post-mortem: 4x4 thread tile = 2.0 LDS-bytes/FMA -> 15.7us LDS floor
// (LDS unit is per-CU, shared by 4 SIMDs -> LDS-bound 3:1 over VALU).
// v3: 128-row tile, K staged in two 64-col halves (Xs[128][68] = 34.8KB,
// + Ws 32KB = 66.8KB LDS, 2 blocks/CU). Thread tile 4 rows x 8 cols:
// 12 ds_read_b128 per 128 FMA = 1.5 B/FMA -> 11.7us LDS floor.
// Row assignment rowg + 32*r: per ds_read instruction the wave's 8 rowgs
// hit bank starts 4g%32 = {0,4,...,28} -> conflict-free. W col-groups are
// 2-way aliased (free, m136).
// ---------------------------------------------------------------------------
__global__ __launch_bounds__(256, 2) void gemm_xw(const float* __restrict__ X,
                                                  const float* __restrict__ W,
                                                  __half* __restrict__ Xp) {
    __shared__ float Xs[BROWS][XS_LD];  // 34.8 KB (one K-half: 64 cols used)
    __shared__ float Ws[D_IN][D_OUT];   // 32 KB

    const int tid  = threadIdx.x;
    const int row0 = blockIdx.x * BROWS;

    // stage W: 8192 floats = 2048 float4, 8 per thread, coalesced
    {
        const float4* W4  = reinterpret_cast<const float4*>(W);
        float4*       Ws4 = reinterpret_cast<float4*>(&Ws[0][0]);
        #pragma unroll
        for (int t = 0; t < 8; ++t) Ws4[tid + 256 * t] = W4[tid + 256 * t];
    }

    const int colg = tid & 7;    // 8 col-groups x 8 cols
    const int rowg = tid >> 3;   // 32 row-groups; rows rowg + 32*r
    const int c0   = colg * 8;

    float acc[4][8];
    #pragma unroll
    for (int r = 0; r < 4; ++r)
        #pragma unroll
        for (int c = 0; c < 8; ++c) acc[r][c] = 0.f;

    const float4* X4 = reinterpret_cast<const float4*>(X);

    for (int h = 0; h < 2; ++h) {
        __syncthreads();   // Xs free (h=0: also covers W staging)
        // stage X K-half: 128 rows x 16 float4; 8 per thread; 256B/row-chunk coalesced
        #pragma unroll
        for (int t = 0; t < 8; ++t) {
            const int s  = tid + 256 * t;  // 0..2047
            const int r  = s >> 4;         // 0..127
            const int q  = s & 15;         // float4 within half-row
            const int gr = row0 + r;
            float4 v = make_float4(0.f, 0.f, 0.f, 0.f);
            if (gr < N_NODES) v = X4[(size_t)gr * 32 + h * 16 + q];
            *reinterpret_cast<float4*>(&Xs[r][q * 4]) = v;
        }
        __syncthreads();

        #pragma unroll
        for (int kq = 0; kq < 16; ++kq) {  // 16 chunks of 4 k within this half
            const int k0 = kq * 4;
            float4 xa[4], wb0[4], wb1[4];
            #pragma unroll
            for (int r = 0; r < 4; ++r)
                xa[r] = *reinterpret_cast<const float4*>(&Xs[rowg + 32 * r][k0]);
            #pragma unroll
            for (int kk = 0; kk < 4; ++kk) {
                wb0[kk] = *reinterpret_cast<const float4*>(&Ws[h * 64 + k0 + kk][c0]);
                wb1[kk] = *reinterpret_cast<const float4*>(&Ws[h * 64 + k0 + kk][c0 + 4]);
            }
            #pragma unroll
            for (int r = 0; r < 4; ++r) {
                const float x0 = xa[r].x, x1 = xa[r].y, x2 = xa[r].z, x3 = xa[r].w;
                acc[r][0] += x0 * wb0[0].x + x1 * wb0[1].x + x2 * wb0[2].x + x3 * wb0[3].x;
                acc[r][1] += x0 * wb0[0].y + x1 * wb0[1].y + x2 * wb0[2].y + x3 * wb0[3].y;
                acc[r][2] += x0 * wb0[0].z + x1 * wb0[1].z + x2 * wb0[2].z + x3 * wb0[3].z;
                acc[r][3] += x0 * wb0[0].w + x1 * wb0[1].w + x2 * wb0[2].w + x3 * wb0[3].w;
                acc[r][4] += x0 * wb1[0].x + x1 * wb1[1].x + x2 * wb1[2].x + x3 * wb1[3].x;
                acc[r][5] += x0 * wb1[0].y + x1 * wb1[1].y + x2 * wb1[2].y + x3 * wb1[3].y;
                acc[r][6] += x0 * wb1[0].z + x1 * wb1[1].z + x2 * wb1[2].z + x3 * wb1[3].z;
                acc[r][7] += x0 * wb1[0].w + x1 * wb1[1].w + x2 * wb1[2].w + x3 * wb1[3].w;
            }
        }
    }

    // epilogue: fp16 store, 16B per row (8 halves), coalesced in 128B runs
    #pragma unroll
    for (int r = 0; r < 4; ++r) {
        const int gr = row0 + rowg + 32 * r;
        if (gr < N_NODES) {
            __half hbuf[8];
            #pragma unroll
            for (int c = 0; c < 8; ++c) hbuf[c] = __float2half(acc[r][c]);
            *reinterpret_cast<float4*>(&Xp[(size_t)gr * D_OUT + c0]) =
                *reinterpret_cast<float4*>(hbuf);
        }
    }
}

// ---------------------------------------------------------------------------
// Kernel 2: row_ptr[i] = lower_bound(row_index, i)
// ---------------------------------------------------------------------------
__global__ __launch_bounds__(256) void build_rowptr(const int* __restrict__ row,
                                                    int* __restrict__ rowptr) {
    const int i = blockIdx.x * 256 + threadIdx.x;
    if (i > N_NODES) return;
    int lo = 0, hi = N_EDGES;
    while (lo < hi) {
        int mid = (lo + hi) >> 1;
        if (row[mid] < i) lo = mid + 1; else hi = mid;
    }
    rowptr[i] = lo;
}

// ---------------------------------------------------------------------------
// Kernel 3: out[i,:] = sum over edges of Xp[col[e],:]. One wave per row,
// lane j owns column j. Xp is fp16 -> per-edge wave transaction = 128B
// (R3: agg was L3-BW-bound at 205MB fp32 gather traffic; fp16 halves it).
// 16-deep batching: avg-degree row = one latency exposure. Every row written
// exactly once -> no memset/atomics.
// ---------------------------------------------------------------------------
__global__ __launch_bounds__(256) void aggregate(const __half* __restrict__ Xp,
                                                 const int* __restrict__ col,
                                                 const int* __restrict__ rowptr,
                                                 float* __restrict__ out) {
    const int wid = (blockIdx.x * 256 + threadIdx.x) >> 6; // row id
    const int j   = threadIdx.x & 63;                      // output col

    const int lo = rowptr[wid];
    const int hi = rowptr[wid + 1];

    float acc = 0.f;
    int e = lo;
    for (; e + 16 <= hi; e += 16) {
        float v[16];
        #pragma unroll
        for (int q = 0; q < 16; ++q)
            v[q] = __half2float(Xp[(size_t)col[e + q] * D_OUT + j]);
        acc += (((v[0] + v[1]) + (v[2] + v[3])) + ((v[4] + v[5]) + (v[6] + v[7])))
             + (((v[8] + v[9]) + (v[10] + v[11])) + ((v[12] + v[13]) + (v[14] + v[15])));
    }
    for (; e + 4 <= hi; e += 4) {
        float v0 = __half2float(Xp[(size_t)col[e + 0] * D_OUT + j]);
        float v1 = __half2float(Xp[(size_t)col[e + 1] * D_OUT + j]);
        float v2 = __half2float(Xp[(size_t)col[e + 2] * D_OUT + j]);
        float v3 = __half2float(Xp[(size_t)col[e + 3] * D_OUT + j]);
        acc += (v0 + v1) + (v2 + v3);
    }
    for (; e < hi; ++e) {
        acc += __half2float(Xp[(size_t)col[e] * D_OUT + j]);
    }
    out[(size_t)wid * D_OUT + j] = acc;
}

// ---------------------------------------------------------------------------
extern "C" void kernel_launch(void* const* d_in, const int* in_sizes, int n_in,
                              void* d_out, int out_size, void* d_ws, size_t ws_size,
                              hipStream_t stream) {
    const float* X   = (const float*)d_in[0];
    const float* W   = (const float*)d_in[1];
    const int*   row = (const int*)d_in[2];
    const int*   col = (const int*)d_in[3];
    float*       out = (float*)d_out;

    // workspace layout: Xp [50000*64 fp16 = 6.4MB] | rowptr [(N+1) i32]
    __half* Xp     = (__half*)d_ws;
    int*    rowptr = (int*)((char*)d_ws + (size_t)N_NODES * D_OUT * sizeof(__half));

    // GEMM: 128-row tiles -> ceil(50000/128) = 391 blocks
    hipLaunchKernelGGL(gemm_xw, dim3((N_NODES + BROWS - 1) / BROWS), dim3(256), 0, stream,
                       X, W, Xp);
    // row_ptr
    hipLaunchKernelGGL(build_rowptr, dim3((N_NODES + 1 + 255) / 256), dim3(256), 0, stream,
                       row, rowptr);
    // aggregation: one wave per row
    hipLaunchKernelGGL(aggregate, dim3((N_NODES * 64) / 256), dim3(256), 0, stream,
                       Xp, col, rowptr, out);
}

// Round 5
// 114.722 us; speedup vs baseline: 3.0540x; 3.0540x over previous
//
#include <hip/hip_runtime.h>
#include <hip/hip_fp16.h>

#define N_NODES 50000
#define D_IN    128
#define D_OUT   64
#define N_EDGES 800000
#define NTILES  (N_NODES / 16)   // 3125 exact — no tail

typedef _Float16 f16x8 __attribute__((ext_vector_type(8)));
typedef float    f32x4 __attribute__((ext_vector_type(4)));

// ---------------------------------------------------------------------------
// Kernel 1: X' = X @ W via fp16 MFMA 16x16x32, fp32 accumulate.
// R4 post-mortem: VALU version spilled (733MB scratch traffic). This version
// keeps per-thread state small: bf[16] (64 VGPR) + acc[4] (16) + xa[8] (32).
// Precision: X split hi+lo fp16 (residual MFMA) -> A rounding eliminated;
// error = W fp16 rounding (~1e-3) + fp16 X' store (same as R4's passing 0.0625).
// Per wave: one 16-row tile; 16 ds_read_b128 (B frags) + 8 global float4 (A)
// + 32 MFMA. W pre-swizzled into LDS in fragment order (one-time per block).
// Fragment maps (guide §3): A[m=lane&15][k=(lane>>4)*8+j + 32ks];
// B[k][n=ct*16+(lane&15)]; D row=(lane>>4)*4+r, col=lane&15 (m89-verified).
// ---------------------------------------------------------------------------
__global__ __launch_bounds__(256) void gemm_xw(const float* __restrict__ X,
                                               const float* __restrict__ W,
                                               _Float16* __restrict__ Xp) {
    // B-fragments pre-arranged: frag f=ct*4+ks, lane l, elem j at Bf[(f*64+l)*8+j]
    __shared__ _Float16 Bf[16 * 64 * 8];   // 16 KB

    const int tid = threadIdx.x;
    #pragma unroll
    for (int i = 0; i < 4; ++i) {
        const int p  = tid + 256 * i;      // fragment-group id 0..1023
        const int l  = p & 63;
        const int f  = p >> 6;             // 0..15
        const int ct = f >> 2, ks = f & 3;
        const int krow = ks * 32 + (l >> 4) * 8;
        const int col  = ct * 16 + (l & 15);
        f16x8 tmp;
        #pragma unroll
        for (int j = 0; j < 8; ++j)
            tmp[j] = (_Float16)W[(krow + j) * D_OUT + col];
        *reinterpret_cast<f16x8*>(&Bf[p * 8]) = tmp;
    }
    __syncthreads();

    const int wid = (blockIdx.x * 256 + tid) >> 6;   // global wave id = row tile
    if (wid >= NTILES) return;
    const int lane = tid & 63;
    const int g    = lane >> 4;    // 0..3
    const int lm   = lane & 15;    // 0..15

    // all 16 B-fragments: one ds_read_b128 each (contiguous 16B/lane -> conflict-free)
    f16x8 bf[16];
    #pragma unroll
    for (int f = 0; f < 16; ++f)
        bf[f] = *reinterpret_cast<const f16x8*>(&Bf[(f * 64 + lane) * 8]);

    // A row for this lane: 8 float4 covering k=0..127 (8 outstanding loads)
    const float4* Xrow = reinterpret_cast<const float4*>(X + (size_t)(wid * 16 + lm) * D_IN);
    float4 xa[8];
    #pragma unroll
    for (int ks = 0; ks < 4; ++ks) {
        xa[2 * ks]     = Xrow[ks * 8 + g * 2];
        xa[2 * ks + 1] = Xrow[ks * 8 + g * 2 + 1];
    }

    f32x4 acc[4];
    #pragma unroll
    for (int ct = 0; ct < 4; ++ct) acc[ct] = (f32x4){0.f, 0.f, 0.f, 0.f};

    #pragma unroll
    for (int ks = 0; ks < 4; ++ks) {
        const float xf[8] = {xa[2*ks].x, xa[2*ks].y, xa[2*ks].z, xa[2*ks].w,
                             xa[2*ks+1].x, xa[2*ks+1].y, xa[2*ks+1].z, xa[2*ks+1].w};
        f16x8 ahi, alo;
        #pragma unroll
        for (int j = 0; j < 8; ++j) {
            const _Float16 h = (_Float16)xf[j];
            ahi[j] = h;
            alo[j] = (_Float16)(xf[j] - (float)h);   // residual: restores fp32-ish A
        }
        #pragma unroll
        for (int ct = 0; ct < 4; ++ct) {
            acc[ct] = __builtin_amdgcn_mfma_f32_16x16x32_f16(ahi, bf[ct * 4 + ks], acc[ct], 0, 0, 0);
            acc[ct] = __builtin_amdgcn_mfma_f32_16x16x32_f16(alo, bf[ct * 4 + ks], acc[ct], 0, 0, 0);
        }
    }

    // D: row = g*4 + r (tile-relative), col = ct*16 + lm; lanes 0-15 form 32B runs
    #pragma unroll
    for (int ct = 0; ct < 4; ++ct)
        #pragma unroll
        for (int r = 0; r < 4; ++r)
            Xp[(size_t)(wid * 16 + g * 4 + r) * D_OUT + ct * 16 + lm] = (_Float16)acc[ct][r];
}

// ---------------------------------------------------------------------------
// Kernel 2: row_ptr[i] = lower_bound(row_index, i)
// ---------------------------------------------------------------------------
__global__ __launch_bounds__(256) void build_rowptr(const int* __restrict__ row,
                                                    int* __restrict__ rowptr) {
    const int i = blockIdx.x * 256 + threadIdx.x;
    if (i > N_NODES) return;
    int lo = 0, hi = N_EDGES;
    while (lo < hi) {
        int mid = (lo + hi) >> 1;
        if (row[mid] < i) lo = mid + 1; else hi = mid;
    }
    rowptr[i] = lo;
}

// ---------------------------------------------------------------------------
// Kernel 3: out[i,:] = sum over edges of fp16 Xp[col[e],:]. One wave per row,
// lane j owns column j; 128B coalesced gather per edge from L2/L3
// (measured R4: ~23us, L3-BW-bound at 102MB logical traffic).
// ---------------------------------------------------------------------------
__global__ __launch_bounds__(256) void aggregate(const __half* __restrict__ Xp,
                                                 const int* __restrict__ col,
                                                 const int* __restrict__ rowptr,
                                                 float* __restrict__ out) {
    const int wid = (blockIdx.x * 256 + threadIdx.x) >> 6; // row id
    const int j   = threadIdx.x & 63;                      // output col

    const int lo = rowptr[wid];
    const int hi = rowptr[wid + 1];

    float acc = 0.f;
    int e = lo;
    for (; e + 16 <= hi; e += 16) {
        float v[16];
        #pragma unroll
        for (int q = 0; q < 16; ++q)
            v[q] = __half2float(Xp[(size_t)col[e + q] * D_OUT + j]);
        acc += (((v[0] + v[1]) + (v[2] + v[3])) + ((v[4] + v[5]) + (v[6] + v[7])))
             + (((v[8] + v[9]) + (v[10] + v[11])) + ((v[12] + v[13]) + (v[14] + v[15])));
    }
    for (; e + 4 <= hi; e += 4) {
        float v0 = __half2float(Xp[(size_t)col[e + 0] * D_OUT + j]);
        float v1 = __half2float(Xp[(size_t)col[e + 1] * D_OUT + j]);
        float v2 = __half2float(Xp[(size_t)col[e + 2] * D_OUT + j]);
        float v3 = __half2float(Xp[(size_t)col[e + 3] * D_OUT + j]);
        acc += (v0 + v1) + (v2 + v3);
    }
    for (; e < hi; ++e) {
        acc += __half2float(Xp[(size_t)col[e] * D_OUT + j]);
    }
    out[(size_t)wid * D_OUT + j] = acc;
}

// ---------------------------------------------------------------------------
extern "C" void kernel_launch(void* const* d_in, const int* in_sizes, int n_in,
                              void* d_out, int out_size, void* d_ws, size_t ws_size,
                              hipStream_t stream) {
    const float* X   = (const float*)d_in[0];
    const float* W   = (const float*)d_in[1];
    const int*   row = (const int*)d_in[2];
    const int*   col = (const int*)d_in[3];
    float*       out = (float*)d_out;

    // workspace layout: Xp [50000*64 fp16 = 6.4MB] | rowptr [(N+1) i32]
    _Float16* Xp     = (_Float16*)d_ws;
    int*      rowptr = (int*)((char*)d_ws + (size_t)N_NODES * D_OUT * sizeof(_Float16));

    // GEMM: 3125 wave-tiles / 4 waves per block = 782 blocks
    hipLaunchKernelGGL(gemm_xw, dim3((NTILES + 3) / 4), dim3(256), 0, stream,
                       X, W, Xp);
    // row_ptr
    hipLaunchKernelGGL(build_rowptr, dim3((N_NODES + 1 + 255) / 256), dim3(256), 0, stream,
                       row, rowptr);
    // aggregation: one wave per row
    hipLaunchKernelGGL(aggregate, dim3((N_NODES * 64) / 256), dim3(256), 0, stream,
                       (const __half*)Xp, col, rowptr, out);
}